// Round 12
// baseline (134.580 us; speedup 1.0000x reference)
//
#include <hip/hip_runtime.h>

#define N_NODES 50000
#define N_EDGES 800000
#define IN_DIM 128
#define OUT_DIM 64

#define GROUP_SHIFT 6                 // 64 rows per group
#define GROUP_ROWS 64
#define N_GROUPS 782                  // ceil(50000/64)
#define SLAB 1216                     // slab capacity per group (mean 1024, +6 sigma)
#define CHUNK 8192                    // edges per fill block
#define FILL_BLOCKS 98                // 98*8192 >= 800000  (fill role on blocks 0..97)

typedef _Float16 h2 __attribute__((ext_vector_type(2)));
typedef _Float16 h4 __attribute__((ext_vector_type(4)));
typedef _Float16 h8 __attribute__((ext_vector_type(8)));
typedef float    f4 __attribute__((ext_vector_type(4)));

#define LDK 136    // padded fp16 K-stride (multiple of 8 -> 16B-aligned b128 rows)

// ---------------------------------------------------------------------------
// D1 (fused, single co-residency wave: 98 fill + 782 gemm = 880 blocks at
// 4 blocks/CU).  Fill role FIRST (blocks 0..97) so its latency hides under
// the gemm blocks.  wt staging uses the register-transpose pack (free 2-way
// bank alias; was 8-way conflicted n-major striding).
// ---------------------------------------------------------------------------
__global__ __launch_bounds__(256) void fused_gemm_fill(const float* __restrict__ x,
                                                       const float* __restrict__ w,
                                                       const int* __restrict__ erow,
                                                       const int* __restrict__ ecol,
                                                       const float* __restrict__ eval,
                                                       _Float16* __restrict__ support,
                                                       int* __restrict__ gcursor,
                                                       int2* __restrict__ bucket) {
    __shared__ char smem[GROUP_ROWS * LDK * 2 + OUT_DIM * LDK * 2];  // 34816 B
    const int tid = threadIdx.x;

    if (blockIdx.x >= FILL_BLOCKS) {
        // ---- GEMM role (blocks 98..879, group = blockIdx-98) ----
        _Float16* xb = (_Float16*)smem;                          // [64][LDK]
        _Float16* wt = (_Float16*)(smem + GROUP_ROWS * LDK * 2); // [64][LDK], wt[n][k]

        // conflict-free wt staging (register transpose, fp16-pair stores)
        {
            const int n_s = tid >> 2;         // 0..63
            const int kp0 = tid & 3;
            #pragma unroll
            for (int it = 0; it < 16; ++it) {
                int kp = kp0 + (it << 2);     // k-pair index 0..63
                int k  = kp << 1;
                h2 hv = { (_Float16)w[(size_t)k * OUT_DIM + n_s],
                          (_Float16)w[(size_t)(k + 1) * OUT_DIM + n_s] };
                *(h2*)&wt[n_s * LDK + k] = hv;
            }
        }
        const int rowbase = (blockIdx.x - FILL_BLOCKS) * GROUP_ROWS;
        for (int i = tid; i < GROUP_ROWS * (IN_DIM / 4); i += 256) {
            int r  = i >> 5;
            int kq = i & 31;
            int row = rowbase + r;
            float4 v = (row < N_NODES)
                           ? *(const float4*)&x[(size_t)row * IN_DIM + kq * 4]
                           : make_float4(0.f, 0.f, 0.f, 0.f);
            h4 hv = { (_Float16)v.x, (_Float16)v.y, (_Float16)v.z, (_Float16)v.w };
            *(h4*)&xb[r * LDK + kq * 4] = hv;
        }
        __syncthreads();

        const int wave = tid >> 6;
        const int lane = tid & 63;
        const int mrow = lane & 15;
        const int quad = lane >> 4;
        const int m0   = wave * 16;

        f4 acc[4];
        #pragma unroll
        for (int t = 0; t < 4; ++t) acc[t] = (f4){0.f, 0.f, 0.f, 0.f};

        #pragma unroll
        for (int ks = 0; ks < 4; ++ks) {
            int kof = ks * 32 + quad * 8;
            h8 a = *(h8*)&xb[(m0 + mrow) * LDK + kof];
            #pragma unroll
            for (int t = 0; t < 4; ++t) {
                h8 b = *(h8*)&wt[(t * 16 + mrow) * LDK + kof];
                acc[t] = __builtin_amdgcn_mfma_f32_16x16x32_f16(a, b, acc[t], 0, 0, 0);
            }
        }

        #pragma unroll
        for (int t = 0; t < 4; ++t) {
            #pragma unroll
            for (int r = 0; r < 4; ++r) {
                int row = rowbase + m0 + quad * 4 + r;
                if (row < N_NODES)
                    support[(size_t)row * OUT_DIM + t * 16 + mrow] = (_Float16)acc[t][r];
            }
        }
    } else {
        // ---- fill role (blocks 0..97) ----
        int* lcnt  = (int*)smem;
        int* lbase = lcnt + N_GROUPS;
        for (int i = tid; i < N_GROUPS; i += 256) lcnt[i] = 0;
        __syncthreads();
        const int base = blockIdx.x * CHUNK;
        #pragma unroll 4
        for (int i = 0; i < CHUNK / 256; ++i) {
            int e = base + tid + i * 256;
            if (e < N_EDGES) atomicAdd(&lcnt[erow[e] >> GROUP_SHIFT], 1);
        }
        __syncthreads();
        for (int i = tid; i < N_GROUPS; i += 256) {
            int c = lcnt[i];
            lbase[i] = c ? atomicAdd(&gcursor[i], c) : 0;
            lcnt[i]  = 0;
        }
        __syncthreads();
        #pragma unroll 4
        for (int i = 0; i < CHUNK / 256; ++i) {
            int e = base + tid + i * 256;
            if (e < N_EDGES) {
                int r = erow[e];
                int g = r >> GROUP_SHIFT;
                int p = atomicAdd(&lcnt[g], 1);
                bucket[(size_t)g * SLAB + lbase[g] + p] =
                    make_int2(((r & (GROUP_ROWS - 1)) << 16) | ecol[e],
                              __float_as_int(eval[e]));
            }
        }
    }
}

// ---------------------------------------------------------------------------
// D2: one 1024-thread block per 64-row group (2 blocks/CU, 32 waves).
// Slab staged to LDS once; histogram + wave-0 scan + in-LDS counting sort;
// one (row, colgroup) per thread; gather loop unrolled x2 with dual
// accumulators for memory-level parallelism; fused ReLU.
// ---------------------------------------------------------------------------
__global__ __launch_bounds__(1024) void reduce_group(const int* __restrict__ gcursor,
                                                     const int2* __restrict__ bucket,
                                                     const _Float16* __restrict__ support,
                                                     float* __restrict__ out) {
    __shared__ int2 ebuf[SLAB];
    __shared__ int2 ebuf2[SLAB];
    __shared__ int  rcnt[GROUP_ROWS];
    __shared__ int  rstart[GROUP_ROWS + 1];
    __shared__ int  rcur[GROUP_ROWS];
    const int grp = blockIdx.x;
    const int cnt = min(gcursor[grp], SLAB);
    const size_t sb = (size_t)grp * SLAB;
    const int tid = threadIdx.x;

    if (tid < GROUP_ROWS) rcnt[tid] = 0;
    __syncthreads();
    for (int j = tid; j < cnt; j += 1024) {
        int2 cv = bucket[sb + j];
        ebuf[j] = cv;
        atomicAdd(&rcnt[cv.x >> 16], 1);
    }
    __syncthreads();
    if (tid < GROUP_ROWS) {
        int v = rcnt[tid];
        int s = v;
        #pragma unroll
        for (int off = 1; off < 64; off <<= 1) {
            int t = __shfl_up(s, off, 64);
            if (tid >= off) s += t;
        }
        rstart[tid] = s - v;
        rcur[tid]   = s - v;
        if (tid == 63) rstart[64] = s;
    }
    __syncthreads();
    for (int j = tid; j < cnt; j += 1024) {
        int2 cv = ebuf[j];
        int rl = cv.x >> 16;
        int p  = atomicAdd(&rcur[rl], 1);
        ebuf2[p] = cv;
    }
    __syncthreads();

    const int g  = tid & 15;
    const int lr = tid >> 4;
    const int row = grp * GROUP_ROWS + lr;
    const int jb = rstart[lr];
    const int je = rstart[lr + 1];
    float4 acc0 = make_float4(0.f, 0.f, 0.f, 0.f);
    float4 acc1 = make_float4(0.f, 0.f, 0.f, 0.f);
    int j = jb;
    for (; j + 1 < je; j += 2) {
        int2 cv0 = ebuf2[j];
        int2 cv1 = ebuf2[j + 1];
        float v0 = __int_as_float(cv0.y);
        float v1 = __int_as_float(cv1.y);
        h4 s0 = *(const h4*)&support[(size_t)(cv0.x & 0xFFFF) * OUT_DIM + g * 4];
        h4 s1 = *(const h4*)&support[(size_t)(cv1.x & 0xFFFF) * OUT_DIM + g * 4];
        acc0.x += v0 * (float)s0[0];
        acc0.y += v0 * (float)s0[1];
        acc0.z += v0 * (float)s0[2];
        acc0.w += v0 * (float)s0[3];
        acc1.x += v1 * (float)s1[0];
        acc1.y += v1 * (float)s1[1];
        acc1.z += v1 * (float)s1[2];
        acc1.w += v1 * (float)s1[3];
    }
    if (j < je) {
        int2 cv = ebuf2[j];
        float v = __int_as_float(cv.y);
        h4 sr = *(const h4*)&support[(size_t)(cv.x & 0xFFFF) * OUT_DIM + g * 4];
        acc0.x += v * (float)sr[0];
        acc0.y += v * (float)sr[1];
        acc0.z += v * (float)sr[2];
        acc0.w += v * (float)sr[3];
    }
    if (row < N_NODES) {
        float4 a;
        a.x = fmaxf(acc0.x + acc1.x, 0.f);
        a.y = fmaxf(acc0.y + acc1.y, 0.f);
        a.z = fmaxf(acc0.z + acc1.z, 0.f);
        a.w = fmaxf(acc0.w + acc1.w, 0.f);
        *(float4*)&out[(size_t)row * OUT_DIM + g * 4] = a;
    }
}

extern "C" void kernel_launch(void* const* d_in, const int* in_sizes, int n_in,
                              void* d_out, int out_size, void* d_ws, size_t ws_size,
                              hipStream_t stream) {
    const float* x    = (const float*)d_in[0];
    const int*   erow = (const int*)  d_in[1];
    const int*   ecol = (const int*)  d_in[2];
    const float* ev   = (const float*)d_in[3];
    const float* w    = (const float*)d_in[4];
    float* out = (float*)d_out;

    // workspace layout (16B-aligned), total ~14.0 MB
    char* ws = (char*)d_ws;
    _Float16* support = (_Float16*)ws;               //  6,400,000 B
    int*  gcursor = (int*)(ws + 6400000);            //      3,128 B
    int2* bucket  = (int2*)(ws + 6403200);           //  7,607,296 B

    hipMemsetAsync(gcursor, 0, sizeof(int) * N_GROUPS, stream);

    fused_gemm_fill<<<FILL_BLOCKS + N_GROUPS, 256, 0, stream>>>(
        x, w, erow, ecol, ev, support, gcursor, bucket);

    reduce_group<<<N_GROUPS, 1024, 0, stream>>>(gcursor, bucket, support, out);
}

// Round 13
// 124.760 us; speedup vs baseline: 1.0787x; 1.0787x over previous
//
#include <hip/hip_runtime.h>

#define N_NODES 50000
#define N_EDGES 800000
#define IN_DIM 128
#define OUT_DIM 64

#define GROUP_SHIFT 6                 // 64 rows per group
#define GROUP_ROWS 64
#define N_GROUPS 782                  // ceil(50000/64)
#define SLAB 1216                     // slab capacity per group (mean 1024, +6 sigma)
#define CHUNK2 2048                   // edges per fill block
#define FILL_BLOCKS 391               // 391*2048 >= 800000 (fill role on blocks 0..390)

typedef _Float16 h2 __attribute__((ext_vector_type(2)));
typedef _Float16 h4 __attribute__((ext_vector_type(4)));
typedef _Float16 h8 __attribute__((ext_vector_type(8)));
typedef float    f4 __attribute__((ext_vector_type(4)));

#define LDK 136    // padded fp16 K-stride (multiple of 8 -> 16B-aligned b128 rows)

// ---------------------------------------------------------------------------
// D1 (fused): blocks [0,391) = fill role (latency-heavy, scheduled FIRST so
// all fill blocks land in the first co-residency wave); blocks [391,1173) =
// MFMA fp16 GEMM per 64-row group (the 149-block second scheduling wave is
// gemm blocks — short and compute-dense).  wt staging: register-transpose
// pack, free 2-way bank alias (was 8-way conflicted).
// ---------------------------------------------------------------------------
__global__ __launch_bounds__(256) void fused_gemm_fill(const float* __restrict__ x,
                                                       const float* __restrict__ w,
                                                       const int* __restrict__ erow,
                                                       const int* __restrict__ ecol,
                                                       const float* __restrict__ eval,
                                                       _Float16* __restrict__ support,
                                                       int* __restrict__ gcursor,
                                                       int2* __restrict__ bucket) {
    __shared__ char smem[GROUP_ROWS * LDK * 2 + OUT_DIM * LDK * 2];  // 34816 B
    const int tid = threadIdx.x;

    if (blockIdx.x >= FILL_BLOCKS) {
        // ---- GEMM role (blocks 391..1172, group = blockIdx-391) ----
        _Float16* xb = (_Float16*)smem;                          // [64][LDK]
        _Float16* wt = (_Float16*)(smem + GROUP_ROWS * LDK * 2); // [64][LDK], wt[n][k]

        // conflict-free wt staging (register transpose, fp16-pair stores)
        {
            const int n_s = tid >> 2;         // 0..63
            const int kp0 = tid & 3;
            #pragma unroll
            for (int it = 0; it < 16; ++it) {
                int kp = kp0 + (it << 2);     // k-pair index 0..63
                int k  = kp << 1;
                h2 hv = { (_Float16)w[(size_t)k * OUT_DIM + n_s],
                          (_Float16)w[(size_t)(k + 1) * OUT_DIM + n_s] };
                *(h2*)&wt[n_s * LDK + k] = hv;
            }
        }
        const int rowbase = (blockIdx.x - FILL_BLOCKS) * GROUP_ROWS;
        for (int i = tid; i < GROUP_ROWS * (IN_DIM / 4); i += 256) {
            int r  = i >> 5;
            int kq = i & 31;
            int row = rowbase + r;
            float4 v = (row < N_NODES)
                           ? *(const float4*)&x[(size_t)row * IN_DIM + kq * 4]
                           : make_float4(0.f, 0.f, 0.f, 0.f);
            h4 hv = { (_Float16)v.x, (_Float16)v.y, (_Float16)v.z, (_Float16)v.w };
            *(h4*)&xb[r * LDK + kq * 4] = hv;
        }
        __syncthreads();

        const int wave = tid >> 6;
        const int lane = tid & 63;
        const int mrow = lane & 15;
        const int quad = lane >> 4;
        const int m0   = wave * 16;

        f4 acc[4];
        #pragma unroll
        for (int t = 0; t < 4; ++t) acc[t] = (f4){0.f, 0.f, 0.f, 0.f};

        #pragma unroll
        for (int ks = 0; ks < 4; ++ks) {
            int kof = ks * 32 + quad * 8;
            h8 a = *(h8*)&xb[(m0 + mrow) * LDK + kof];
            #pragma unroll
            for (int t = 0; t < 4; ++t) {
                h8 b = *(h8*)&wt[(t * 16 + mrow) * LDK + kof];
                acc[t] = __builtin_amdgcn_mfma_f32_16x16x32_f16(a, b, acc[t], 0, 0, 0);
            }
        }

        #pragma unroll
        for (int t = 0; t < 4; ++t) {
            #pragma unroll
            for (int r = 0; r < 4; ++r) {
                int row = rowbase + m0 + quad * 4 + r;
                if (row < N_NODES)
                    support[(size_t)row * OUT_DIM + t * 16 + mrow] = (_Float16)acc[t][r];
            }
        }
    } else {
        // ---- fill role (blocks 0..390) ----
        int* lcnt  = (int*)smem;
        int* lbase = lcnt + N_GROUPS;
        for (int i = tid; i < N_GROUPS; i += 256) lcnt[i] = 0;
        __syncthreads();
        const int base = blockIdx.x * CHUNK2;
        #pragma unroll 4
        for (int i = 0; i < CHUNK2 / 256; ++i) {
            int e = base + tid + i * 256;
            if (e < N_EDGES) atomicAdd(&lcnt[erow[e] >> GROUP_SHIFT], 1);
        }
        __syncthreads();
        for (int i = tid; i < N_GROUPS; i += 256) {
            int c = lcnt[i];
            lbase[i] = c ? atomicAdd(&gcursor[i], c) : 0;
            lcnt[i]  = 0;
        }
        __syncthreads();
        #pragma unroll 4
        for (int i = 0; i < CHUNK2 / 256; ++i) {
            int e = base + tid + i * 256;
            if (e < N_EDGES) {
                int r = erow[e];
                int g = r >> GROUP_SHIFT;
                int p = atomicAdd(&lcnt[g], 1);
                bucket[(size_t)g * SLAB + lbase[g] + p] =
                    make_int2(((r & (GROUP_ROWS - 1)) << 16) | ecol[e],
                              __float_as_int(eval[e]));
            }
        }
    }
}

// ---------------------------------------------------------------------------
// D2: one 1024-thread block per 64-row group (2 blocks/CU, 32 waves).
// Slab staged to LDS once; histogram + wave-0 scan + in-LDS counting sort;
// one (row, colgroup) per thread; gather loop unrolled x2 with dual
// accumulators; fused ReLU.
// ---------------------------------------------------------------------------
__global__ __launch_bounds__(1024) void reduce_group(const int* __restrict__ gcursor,
                                                     const int2* __restrict__ bucket,
                                                     const _Float16* __restrict__ support,
                                                     float* __restrict__ out) {
    __shared__ int2 ebuf[SLAB];
    __shared__ int2 ebuf2[SLAB];
    __shared__ int  rcnt[GROUP_ROWS];
    __shared__ int  rstart[GROUP_ROWS + 1];
    __shared__ int  rcur[GROUP_ROWS];
    const int grp = blockIdx.x;
    const int cnt = min(gcursor[grp], SLAB);
    const size_t sb = (size_t)grp * SLAB;
    const int tid = threadIdx.x;

    if (tid < GROUP_ROWS) rcnt[tid] = 0;
    __syncthreads();
    for (int j = tid; j < cnt; j += 1024) {
        int2 cv = bucket[sb + j];
        ebuf[j] = cv;
        atomicAdd(&rcnt[cv.x >> 16], 1);
    }
    __syncthreads();
    if (tid < GROUP_ROWS) {
        int v = rcnt[tid];
        int s = v;
        #pragma unroll
        for (int off = 1; off < 64; off <<= 1) {
            int t = __shfl_up(s, off, 64);
            if (tid >= off) s += t;
        }
        rstart[tid] = s - v;
        rcur[tid]   = s - v;
        if (tid == 63) rstart[64] = s;
    }
    __syncthreads();
    for (int j = tid; j < cnt; j += 1024) {
        int2 cv = ebuf[j];
        int rl = cv.x >> 16;
        int p  = atomicAdd(&rcur[rl], 1);
        ebuf2[p] = cv;
    }
    __syncthreads();

    const int g  = tid & 15;
    const int lr = tid >> 4;
    const int row = grp * GROUP_ROWS + lr;
    const int jb = rstart[lr];
    const int je = rstart[lr + 1];
    float4 acc0 = make_float4(0.f, 0.f, 0.f, 0.f);
    float4 acc1 = make_float4(0.f, 0.f, 0.f, 0.f);
    int j = jb;
    for (; j + 1 < je; j += 2) {
        int2 cv0 = ebuf2[j];
        int2 cv1 = ebuf2[j + 1];
        float v0 = __int_as_float(cv0.y);
        float v1 = __int_as_float(cv1.y);
        h4 s0 = *(const h4*)&support[(size_t)(cv0.x & 0xFFFF) * OUT_DIM + g * 4];
        h4 s1 = *(const h4*)&support[(size_t)(cv1.x & 0xFFFF) * OUT_DIM + g * 4];
        acc0.x += v0 * (float)s0[0];
        acc0.y += v0 * (float)s0[1];
        acc0.z += v0 * (float)s0[2];
        acc0.w += v0 * (float)s0[3];
        acc1.x += v1 * (float)s1[0];
        acc1.y += v1 * (float)s1[1];
        acc1.z += v1 * (float)s1[2];
        acc1.w += v1 * (float)s1[3];
    }
    if (j < je) {
        int2 cv = ebuf2[j];
        float v = __int_as_float(cv.y);
        h4 sr = *(const h4*)&support[(size_t)(cv.x & 0xFFFF) * OUT_DIM + g * 4];
        acc0.x += v * (float)sr[0];
        acc0.y += v * (float)sr[1];
        acc0.z += v * (float)sr[2];
        acc0.w += v * (float)sr[3];
    }
    if (row < N_NODES) {
        float4 a;
        a.x = fmaxf(acc0.x + acc1.x, 0.f);
        a.y = fmaxf(acc0.y + acc1.y, 0.f);
        a.z = fmaxf(acc0.z + acc1.z, 0.f);
        a.w = fmaxf(acc0.w + acc1.w, 0.f);
        *(float4*)&out[(size_t)row * OUT_DIM + g * 4] = a;
    }
}

extern "C" void kernel_launch(void* const* d_in, const int* in_sizes, int n_in,
                              void* d_out, int out_size, void* d_ws, size_t ws_size,
                              hipStream_t stream) {
    const float* x    = (const float*)d_in[0];
    const int*   erow = (const int*)  d_in[1];
    const int*   ecol = (const int*)  d_in[2];
    const float* ev   = (const float*)d_in[3];
    const float* w    = (const float*)d_in[4];
    float* out = (float*)d_out;

    // workspace layout (16B-aligned), total ~14.0 MB
    char* ws = (char*)d_ws;
    _Float16* support = (_Float16*)ws;               //  6,400,000 B
    int*  gcursor = (int*)(ws + 6400000);            //      3,128 B
    int2* bucket  = (int2*)(ws + 6403200);           //  7,607,296 B

    hipMemsetAsync(gcursor, 0, sizeof(int) * N_GROUPS, stream);

    fused_gemm_fill<<<FILL_BLOCKS + N_GROUPS, 256, 0, stream>>>(
        x, w, erow, ecol, ev, support, gcursor, bucket);

    reduce_group<<<N_GROUPS, 1024, 0, stream>>>(gcursor, bucket, support, out);
}